// Round 1
// baseline (40.123 us; speedup 1.0000x reference)
//
#include <hip/hip_runtime.h>

#define TPB 256
#define NBLK 682            // 174592 / 256
#define GNUM 50
#define INF_ 1000000.0f

__global__ __launch_bounds__(TPB) void fcos_main(
    const float* __restrict__ pred_class,
    const float4* __restrict__ pred_bbox,
    const float* __restrict__ pred_ctr,
    const float4* __restrict__ gt_boxes,
    const int* __restrict__ gt_labels,
    float* __restrict__ partials)
{
    __shared__ int lds_lab[TPB];
    __shared__ float wpart[4][5];

    const int tid = threadIdx.x;
    const int k = blockIdx.x * TPB + tid;

    // ---- decode flat index -> (level, batch, point) ----
    // flat order: level-major, then batch, then point. All boundaries are
    // multiples of 256, so each block is level-uniform (branches are uniform).
    int li, b, p;
    if (k < 131072)      { li = 0; int r = k;          b = r >> 14; p = r & 16383; }
    else if (k < 163840) { li = 1; int r = k - 131072; b = r >> 12; p = r & 4095; }
    else if (k < 172032) { li = 2; int r = k - 163840; b = r >> 10; p = r & 1023; }
    else if (k < 174080) { li = 3; int r = k - 172032; b = r >> 8;  p = r & 255; }
    else                 { li = 4; int r = k - 174080; b = r >> 6;  p = r & 63; }

    const int logn = 7 - li;                    // n = 128 >> li
    const float sF = (float)(8 << li);          // stride
    const float x = ((float)(p & ((1 << logn) - 1)) + 0.5f) * sF;  // col -> x
    const float y = ((float)(p >> logn) + 0.5f) * sF;              // row -> y
    const float lo = (li == 0) ? -1.0f : (float)(64 << (li - 1));
    const float hi = (li == 4) ? INF_ : (float)(64 << li);

    // ---- GT assignment: argmin of masked area (first-occurrence tie-break) ----
    const float4* gb = gt_boxes + b * GNUM;
    float best = INF_;
    int bi = 0;
    float wl = 0.f, wt = 0.f, wr = 0.f, wb = 0.f;
    #pragma unroll 5
    for (int g = 0; g < GNUM; ++g) {
        float4 bx = gb[g];
        float l  = x - bx.x;
        float t  = y - bx.y;
        float r  = bx.z - x;
        float bt = bx.w - y;
        float mn = fminf(fminf(l, t), fminf(r, bt));
        float mx = fmaxf(fmaxf(l, t), fmaxf(r, bt));
        float area = (bx.z - bx.x) * (bx.w - bx.y);
        bool ok = (mn > 0.0f) && (mx >= lo) && (mx <= hi);
        float m = ok ? area : INF_;
        if (m < best) { best = m; bi = g; wl = l; wt = t; wr = r; wb = bt; }
    }

    const bool pos = best < INF_;   // min_area >= INF  <=>  no valid GT
    float ctr = 0.0f, lbox = 0.0f, bce = 0.0f;
    int lab = -1;
    if (pos) {
        lab = gt_labels[b * GNUM + bi] - 1;     // 0..79
        // centerness target
        float num = fminf(wl, wr) * fminf(wt, wb);
        float den = fmaxf(wl, wr) * fmaxf(wt, wb) + 1e-12f;
        ctr = sqrtf(fminf(fmaxf(num / den, 0.0f), 1.0f));

        // IoU loss term (negatives: ctr=0 -> exact 0 contribution in ref)
        float4 d = pred_bbox[k];
        float px1 = x - d.x, py1 = y - d.y, px2 = x + d.z, py2 = y + d.w;
        float tx1 = x - wl,  ty1 = y - wt,  tx2 = x + wr,  ty2 = y + wb;
        float ix1 = fmaxf(px1, tx1), iy1 = fmaxf(py1, ty1);
        float ix2 = fminf(px2, tx2), iy2 = fminf(py2, ty2);
        float inter = fmaxf(ix2 - ix1, 0.0f) * fmaxf(iy2 - iy1, 0.0f);
        float ap = fmaxf(px2 - px1, 0.0f) * fmaxf(py2 - py1, 0.0f);
        float at = fmaxf(tx2 - tx1, 0.0f) * fmaxf(ty2 - ty1, 0.0f);
        float iou = inter / (ap + at - inter + 1e-7f);
        lbox = -__logf(fminf(fmaxf(iou, 1e-6f), 1.0f)) * ctr;

        // centerness BCE (weighted by posf -> positives only)
        float pc = pred_ctr[k];
        float e  = __expf(-fabsf(pc));
        float l1 = __logf(1.0f + e);
        float sp_p = fmaxf(pc, 0.0f) + l1;     // softplus(pc)  = -log_sigmoid(-pc)
        float sp_n = fmaxf(-pc, 0.0f) + l1;    // softplus(-pc) = -log_sigmoid(pc)
        bce = ctr * sp_n + (1.0f - ctr) * sp_p;
    }
    lds_lab[tid] = lab;
    __syncthreads();

    // ---- phase 2: focal classification loss, coalesced float4 over 256x80 ----
    float cls = 0.0f;
    const float4* pc4 = (const float4*)pred_class + (size_t)blockIdx.x * (TPB * 20);
    #pragma unroll 4
    for (int it = 0; it < 20; ++it) {
        int c4 = tid + it * TPB;            // 0..5119
        float4 v = pc4[c4];
        int pl = c4 / 20;                   // local point 0..255
        int cb = (c4 - pl * 20) * 4;        // class base 0,4,...,76
        int labp = lds_lab[pl];
        float vv[4] = {v.x, v.y, v.z, v.w};
        #pragma unroll
        for (int j = 0; j < 4; ++j) {
            float xx = vv[j];
            float e  = __expf(-fabsf(xx));
            float l1 = __logf(1.0f + e);
            float pr = ((xx >= 0.0f) ? 1.0f : e) / (1.0f + e);   // sigmoid(xx)
            if (cb + j == labp) {
                float q = 1.0f - pr;
                cls += 0.25f * q * q * (fmaxf(-xx, 0.0f) + l1);  // 0.25*(1-p)^2*softplus(-x)
            } else {
                cls += 0.75f * pr * pr * (fmaxf(xx, 0.0f) + l1); // 0.75*p^2*softplus(x)
            }
        }
    }

    // ---- deterministic block reduction of 5 sums ----
    float v5[5] = {cls, lbox, bce, pos ? 1.0f : 0.0f, ctr};
    #pragma unroll
    for (int off = 32; off >= 1; off >>= 1) {
        #pragma unroll
        for (int s2 = 0; s2 < 5; ++s2) v5[s2] += __shfl_down(v5[s2], off);
    }
    const int lane = tid & 63, wid = tid >> 6;
    if (lane == 0) {
        #pragma unroll
        for (int s2 = 0; s2 < 5; ++s2) wpart[wid][s2] = v5[s2];
    }
    __syncthreads();
    if (tid == 0) {
        #pragma unroll
        for (int s2 = 0; s2 < 5; ++s2)
            partials[s2 * NBLK + blockIdx.x] =
                wpart[0][s2] + wpart[1][s2] + wpart[2][s2] + wpart[3][s2];
    }
}

__global__ __launch_bounds__(TPB) void fcos_final(
    const float* __restrict__ partials, float* __restrict__ out)
{
    const int tid = threadIdx.x;
    float acc[5] = {0, 0, 0, 0, 0};
    for (int i = tid; i < NBLK; i += TPB) {
        #pragma unroll
        for (int s2 = 0; s2 < 5; ++s2) acc[s2] += partials[s2 * NBLK + i];
    }
    #pragma unroll
    for (int off = 32; off >= 1; off >>= 1) {
        #pragma unroll
        for (int s2 = 0; s2 < 5; ++s2) acc[s2] += __shfl_down(acc[s2], off);
    }
    __shared__ float wp[4][5];
    const int lane = tid & 63, wid = tid >> 6;
    if (lane == 0) {
        #pragma unroll
        for (int s2 = 0; s2 < 5; ++s2) wp[wid][s2] = acc[s2];
    }
    __syncthreads();
    if (tid == 0) {
        float S[5];
        #pragma unroll
        for (int s2 = 0; s2 < 5; ++s2)
            S[s2] = wp[0][s2] + wp[1][s2] + wp[2][s2] + wp[3][s2];
        float pos_num = fmaxf(S[3], 1.0f);
        float denorm  = fmaxf(S[4], 1e-6f);
        out[0] = S[0] / pos_num;   // loss_cls
        out[1] = S[1] / denorm;    // loss_box
        out[2] = S[2] / pos_num;   // loss_ctr
    }
}

extern "C" void kernel_launch(void* const* d_in, const int* in_sizes, int n_in,
                              void* d_out, int out_size, void* d_ws, size_t ws_size,
                              hipStream_t stream) {
    const float*  pred_class = (const float*)d_in[0];
    const float4* pred_bbox  = (const float4*)d_in[1];
    const float*  pred_ctr   = (const float*)d_in[2];
    const float4* gt_boxes   = (const float4*)d_in[3];
    const int*    gt_labels  = (const int*)d_in[4];
    float* partials = (float*)d_ws;          // 5 * NBLK floats, fully rewritten each call
    float* out = (float*)d_out;

    fcos_main<<<NBLK, TPB, 0, stream>>>(pred_class, pred_bbox, pred_ctr,
                                        gt_boxes, gt_labels, partials);
    fcos_final<<<1, TPB, 0, stream>>>(partials, out);
}

// Round 2
// 34.353 us; speedup vs baseline: 1.1679x; 1.1679x over previous
//
#include <hip/hip_runtime.h>

#define TPB 256
#define PPB 64              // points per block
#define NBLK 2728           // 174592 / 64
#define GNUM 50
#define INF_ 1000000.0f

__global__ __launch_bounds__(TPB) void fcos_main(
    const float* __restrict__ pred_class,
    const float4* __restrict__ pred_bbox,
    const float* __restrict__ pred_ctr,
    const float4* __restrict__ gt_boxes,
    const int* __restrict__ gt_labels,
    float* __restrict__ partials)
{
    __shared__ int lds_lab[PPB];
    __shared__ float wpart[4][5];

    const int tid = threadIdx.x;
    const int sub = tid & 3;        // 4 lanes cooperate on one point
    const int pt  = tid >> 2;       // local point 0..63
    const int k0  = blockIdx.x << 6;
    const int k   = k0 + pt;        // this group's global point index

    // ---- decode block -> (level, batch, point-base); uniform per block ----
    // All (level,batch) segment boundaries are multiples of 64.
    int li, b, p0;
    if (k0 < 131072)      { li = 0; int r = k0;          b = r >> 14; p0 = r & 16383; }
    else if (k0 < 163840) { li = 1; int r = k0 - 131072; b = r >> 12; p0 = r & 4095; }
    else if (k0 < 172032) { li = 2; int r = k0 - 163840; b = r >> 10; p0 = r & 1023; }
    else if (k0 < 174080) { li = 3; int r = k0 - 172032; b = r >> 8;  p0 = r & 255; }
    else                  { li = 4; int r = k0 - 174080; b = r >> 6;  p0 = r & 63; }

    const int p = p0 + pt;
    const int logn = 7 - li;                    // n = 128 >> li
    const float sF = (float)(8 << li);          // stride
    const float x = ((float)(p & ((1 << logn) - 1)) + 0.5f) * sF;
    const float y = ((float)(p >> logn) + 0.5f) * sF;
    const float lo = (li == 0) ? -1.0f : (float)(64 << (li - 1));
    const float hi = (li == 4) ? INF_ : (float)(64 << li);

    // ---- GT assignment: 4 lanes scan 13 contiguous GTs each ----
    const float4* gb = gt_boxes + b * GNUM;
    float best = INF_;
    int bi = GNUM;                  // sentinel > any valid idx for tie-break
    #pragma unroll
    for (int j = 0; j < 13; ++j) {
        int g = sub * 13 + j;       // contiguous chunk keeps ordering
        int gg = min(g, GNUM - 1);
        float4 bx = gb[gg];
        float l  = x - bx.x;
        float t  = y - bx.y;
        float r  = bx.z - x;
        float bt = bx.w - y;
        float mn = fminf(fminf(l, t), fminf(r, bt));
        float mx = fmaxf(fmaxf(l, t), fmaxf(r, bt));
        float area = (bx.z - bx.x) * (bx.w - bx.y);
        bool ok = (mn > 0.0f) && (mx >= lo) && (mx <= hi) && (g < GNUM);
        float m = ok ? area : INF_;
        if (m < best) { best = m; bi = g; }     // strict < = first occurrence in chunk
    }
    // lexicographic (area, idx) min across the 4 sub-lanes
    #pragma unroll
    for (int off = 1; off <= 2; off <<= 1) {
        float ob = __shfl_xor(best, off);
        int   oi = __shfl_xor(bi, off);
        if (ob < best || (ob == best && oi < bi)) { best = ob; bi = oi; }
    }

    const bool pos = best < INF_;
    float ctr = 0.0f, lbox = 0.0f, bce = 0.0f, posf = 0.0f;
    int lab = -1;
    if (sub == 0) {
        if (pos) {
            posf = 1.0f;
            lab = gt_labels[b * GNUM + bi] - 1;     // 0..79
            float4 bx = gb[bi];                     // recompute winner ltrb
            float wl = x - bx.x, wt = y - bx.y, wr = bx.z - x, wb = bx.w - y;

            float num = fminf(wl, wr) * fminf(wt, wb);
            float den = fmaxf(wl, wr) * fmaxf(wt, wb) + 1e-12f;
            ctr = sqrtf(fminf(fmaxf(num * __builtin_amdgcn_rcpf(den), 0.0f), 1.0f));

            float4 d = pred_bbox[k];
            float px1 = x - d.x, py1 = y - d.y, px2 = x + d.z, py2 = y + d.w;
            float tx1 = x - wl,  ty1 = y - wt,  tx2 = x + wr,  ty2 = y + wb;
            float ix1 = fmaxf(px1, tx1), iy1 = fmaxf(py1, ty1);
            float ix2 = fminf(px2, tx2), iy2 = fminf(py2, ty2);
            float inter = fmaxf(ix2 - ix1, 0.0f) * fmaxf(iy2 - iy1, 0.0f);
            float ap = fmaxf(px2 - px1, 0.0f) * fmaxf(py2 - py1, 0.0f);
            float at = fmaxf(tx2 - tx1, 0.0f) * fmaxf(ty2 - ty1, 0.0f);
            float iou = inter * __builtin_amdgcn_rcpf(ap + at - inter + 1e-7f);
            lbox = -__logf(fminf(fmaxf(iou, 1e-6f), 1.0f)) * ctr;

            float pc = pred_ctr[k];
            float e  = __expf(-fabsf(pc));
            float l1 = __logf(1.0f + e);
            float sp_p = fmaxf(pc, 0.0f) + l1;     // softplus(pc)
            float sp_n = fmaxf(-pc, 0.0f) + l1;    // softplus(-pc)
            bce = ctr * sp_n + (1.0f - ctr) * sp_p;
        }
        lds_lab[pt] = lab;
    }
    __syncthreads();

    // ---- phase 2: focal classification loss, 64 pts x 80 cls, float4 ----
    float cls = 0.0f;
    const float4* pc4 = (const float4*)pred_class + (size_t)blockIdx.x * (PPB * 20);
    #pragma unroll
    for (int it = 0; it < 5; ++it) {
        int c4 = tid + it * TPB;            // 0..1279
        float4 v = pc4[c4];
        int pl = c4 / 20;                   // local point 0..63
        int cb = (c4 - pl * 20) * 4;        // class base
        int labp = lds_lab[pl];
        float vv[4] = {v.x, v.y, v.z, v.w};
        #pragma unroll
        for (int j = 0; j < 4; ++j) {
            float xx = vv[j];
            float e  = __expf(-fabsf(xx));
            float d  = 1.0f + e;
            float r  = __builtin_amdgcn_rcpf(d);
            float ln = __logf(d);
            float mx0 = fmaxf(xx, 0.0f);
            float pr = ((xx >= 0.0f) ? 1.0f : e) * r;   // sigmoid(xx)
            float a, sp;
            if (cb + j == labp) {
                float q = 1.0f - pr;
                a = 0.25f * q * q;  sp = (mx0 - xx) + ln;   // softplus(-x)
            } else {
                a = 0.75f * pr * pr; sp = mx0 + ln;         // softplus(x)
            }
            cls = fmaf(a, sp, cls);
        }
    }

    // ---- deterministic block reduction of 5 sums ----
    float v5[5] = {cls, lbox, bce, posf, ctr};
    #pragma unroll
    for (int off = 32; off >= 1; off >>= 1) {
        #pragma unroll
        for (int s2 = 0; s2 < 5; ++s2) v5[s2] += __shfl_down(v5[s2], off);
    }
    const int lane = tid & 63, wid = tid >> 6;
    if (lane == 0) {
        #pragma unroll
        for (int s2 = 0; s2 < 5; ++s2) wpart[wid][s2] = v5[s2];
    }
    __syncthreads();
    if (tid == 0) {
        #pragma unroll
        for (int s2 = 0; s2 < 5; ++s2)
            partials[s2 * NBLK + blockIdx.x] =
                wpart[0][s2] + wpart[1][s2] + wpart[2][s2] + wpart[3][s2];
    }
}

__global__ __launch_bounds__(TPB) void fcos_final(
    const float* __restrict__ partials, float* __restrict__ out)
{
    const int tid = threadIdx.x;
    float acc[5] = {0, 0, 0, 0, 0};
    for (int i = tid; i < NBLK; i += TPB) {
        #pragma unroll
        for (int s2 = 0; s2 < 5; ++s2) acc[s2] += partials[s2 * NBLK + i];
    }
    #pragma unroll
    for (int off = 32; off >= 1; off >>= 1) {
        #pragma unroll
        for (int s2 = 0; s2 < 5; ++s2) acc[s2] += __shfl_down(acc[s2], off);
    }
    __shared__ float wp[4][5];
    const int lane = tid & 63, wid = tid >> 6;
    if (lane == 0) {
        #pragma unroll
        for (int s2 = 0; s2 < 5; ++s2) wp[wid][s2] = acc[s2];
    }
    __syncthreads();
    if (tid == 0) {
        float S[5];
        #pragma unroll
        for (int s2 = 0; s2 < 5; ++s2)
            S[s2] = wp[0][s2] + wp[1][s2] + wp[2][s2] + wp[3][s2];
        float pos_num = fmaxf(S[3], 1.0f);
        float denorm  = fmaxf(S[4], 1e-6f);
        out[0] = S[0] / pos_num;   // loss_cls
        out[1] = S[1] / denorm;    // loss_box
        out[2] = S[2] / pos_num;   // loss_ctr
    }
}

extern "C" void kernel_launch(void* const* d_in, const int* in_sizes, int n_in,
                              void* d_out, int out_size, void* d_ws, size_t ws_size,
                              hipStream_t stream) {
    const float*  pred_class = (const float*)d_in[0];
    const float4* pred_bbox  = (const float4*)d_in[1];
    const float*  pred_ctr   = (const float*)d_in[2];
    const float4* gt_boxes   = (const float4*)d_in[3];
    const int*    gt_labels  = (const int*)d_in[4];
    float* partials = (float*)d_ws;          // 5 * NBLK floats, fully rewritten each call
    float* out = (float*)d_out;

    fcos_main<<<NBLK, TPB, 0, stream>>>(pred_class, pred_bbox, pred_ctr,
                                        gt_boxes, gt_labels, partials);
    fcos_final<<<1, TPB, 0, stream>>>(partials, out);
}